// Round 1
// baseline (2530.238 us; speedup 1.0000x reference)
//
#include <hip/hip_runtime.h>

typedef unsigned short u16;
typedef short bf16x8 __attribute__((ext_vector_type(8)));
typedef float f32x4 __attribute__((ext_vector_type(4)));

#define VOCAB 32000

__device__ __forceinline__ u16 f2bf(float f) {
  union { float f; unsigned u; } c; c.f = f;
  unsigned u = c.u;
  return (u16)((u + 0x7fffu + ((u >> 16) & 1u)) >> 16);
}

__device__ __forceinline__ float gelu_f(float x) {
  return 0.5f * x * (1.0f + tanhf(0.7978845608028654f * (x + 0.044715f * x * x * x)));
}

__device__ __forceinline__ void gload16(void* lds, const void* g) {
  __builtin_amdgcn_global_load_lds(
      (const __attribute__((address_space(1))) void*)g,
      (__attribute__((address_space(3))) void*)lds, 16, 0, 0);
}

// ---------------- embedding ----------------
__global__ __launch_bounds__(256)
void embed_kernel(const int* __restrict__ tok_ids, const float* __restrict__ tok_emb,
                  const float* __restrict__ pos_emb, const float* __restrict__ mask_tok,
                  float* __restrict__ x)
{
  const int r = blockIdx.x;       // 0..4095 = b*2048 + s
  const int b = r >> 11;
  const int s = r & 2047;
  const float* src;
  int p;
  if (s < 1024) { src = tok_emb + (size_t)tok_ids[(b << 10) + s] * 512; p = s; }
  else          { src = mask_tok + (size_t)((s - 1024) & 15) * 512;     p = s - 1024; }
  const float* pe = pos_emb + (size_t)p * 512;
  float* xr = x + (size_t)r * 512;
  for (int c = threadIdx.x; c < 512; c += 256) xr[c] = src[c] + pe[c];
}

// ---------------- layernorm (f32 in -> bf16 out) ----------------
__global__ __launch_bounds__(256)
void ln_kernel(const float* __restrict__ x, const float* __restrict__ gs,
               const float* __restrict__ gb, u16* __restrict__ out)
{
  const int row = blockIdx.x;
  const float* xr = x + (size_t)row * 512;
  const int tid = threadIdx.x;
  const float v0 = xr[tid], v1 = xr[tid + 256];
  float s = v0 + v1, q = v0 * v0 + v1 * v1;
  #pragma unroll
  for (int o = 32; o; o >>= 1) { s += __shfl_xor(s, o); q += __shfl_xor(q, o); }
  __shared__ float rs[4], rq[4];
  const int w = tid >> 6;
  if ((tid & 63) == 0) { rs[w] = s; rq[w] = q; }
  __syncthreads();
  s = rs[0] + rs[1] + rs[2] + rs[3];
  q = rq[0] + rq[1] + rq[2] + rq[3];
  const float mean = s * (1.0f / 512.0f);
  const float var  = q * (1.0f / 512.0f) - mean * mean;
  const float inv  = rsqrtf(var + 1e-5f);
  out[(size_t)row * 512 + tid]       = f2bf((v0 - mean) * inv * gs[tid] + gb[tid]);
  out[(size_t)row * 512 + tid + 256] = f2bf((v1 - mean) * inv * gs[tid + 256] + gb[tid + 256]);
}

// ---------------- weight prep ----------------
// src (K,N) f32 row-major -> dst (N,K) bf16 row-major
__global__ __launch_bounds__(256)
void transpose_cast_kernel(const float* __restrict__ src, u16* __restrict__ dst,
                           int K, int N)
{
  __shared__ float tile[32][33];
  const int nb = blockIdx.x << 5;
  const int kb = blockIdx.y << 5;
  const int tx = threadIdx.x, ty = threadIdx.y;   // 32 x 8
  #pragma unroll
  for (int i = 0; i < 32; i += 8)
    tile[ty + i][tx] = src[(size_t)(kb + ty + i) * N + nb + tx];
  __syncthreads();
  #pragma unroll
  for (int i = 0; i < 32; i += 8)
    dst[(size_t)(nb + ty + i) * K + kb + tx] = f2bf(tile[tx][ty + i]);
}

__global__ __launch_bounds__(256)
void cast_bf16_kernel(const float* __restrict__ src, u16* __restrict__ dst, int n)
{
  const int i = (blockIdx.x * 256 + threadIdx.x) * 4;
  if (i + 3 < n) {
    const float4 v = *(const float4*)(src + i);
    ushort4 pk = make_ushort4(f2bf(v.x), f2bf(v.y), f2bf(v.z), f2bf(v.w));
    *(ushort4*)(dst + i) = pk;
  }
}

// ---------------- GEMM: C = A(MxK,bf16) @ Bt(NxK,bf16)^T (+bias) ----------------
// EPI: 0 = bias, bf16 out; 1 = bias+gelu, bf16 out; 2 = bias, += into f32 resid;
//      3 = no bias, f32 out
template<int EPI>
__global__ __launch_bounds__(256, 2)
void gemm_kernel(const u16* __restrict__ A, const u16* __restrict__ Bt,
                 const float* __restrict__ bias, u16* __restrict__ obf,
                 float* __restrict__ of32, int M, int N, int K)
{
  __shared__ u16 As[128 * 64];
  __shared__ u16 Bs[128 * 64];
  const int tid = threadIdx.x;
  const int lane = tid & 63;
  const int w = tid >> 6;
  const int m0 = blockIdx.y << 7;
  const int n0 = blockIdx.x << 7;
  const int wr = w >> 1, wc = w & 1;

  f32x4 acc[4][4] = {};

  const u16* Ag = A  + (size_t)(m0 + (lane >> 3)) * K + ((lane & 7) << 3);
  const u16* Bg = Bt + (size_t)(n0 + (lane >> 3)) * K + ((lane & 7) << 3);

  for (int k0 = 0; k0 < K; k0 += 64) {
    __syncthreads();
    #pragma unroll
    for (int i = 0; i < 4; ++i) {
      const int r = (w << 5) + (i << 3);
      gload16(&As[r * 64], Ag + (size_t)r * K + k0);
      gload16(&Bs[r * 64], Bg + (size_t)r * K + k0);
    }
    __syncthreads();
    #pragma unroll
    for (int kk = 0; kk < 2; ++kk) {
      bf16x8 af[4], bfr[4];
      #pragma unroll
      for (int i = 0; i < 4; ++i) {
        af[i]  = *(const bf16x8*)&As[(wr * 64 + i * 16 + (lane & 15)) * 64 + kk * 32 + (lane >> 4) * 8];
        bfr[i] = *(const bf16x8*)&Bs[(wc * 64 + i * 16 + (lane & 15)) * 64 + kk * 32 + (lane >> 4) * 8];
      }
      #pragma unroll
      for (int mi = 0; mi < 4; ++mi)
        #pragma unroll
        for (int ni = 0; ni < 4; ++ni)
          acc[mi][ni] = __builtin_amdgcn_mfma_f32_16x16x32_bf16(af[mi], bfr[ni], acc[mi][ni], 0, 0, 0);
    }
  }

  #pragma unroll
  for (int mi = 0; mi < 4; ++mi) {
    #pragma unroll
    for (int ni = 0; ni < 4; ++ni) {
      const int row = m0 + wr * 64 + mi * 16 + ((lane >> 4) << 2);
      const int col = n0 + wc * 64 + ni * 16 + (lane & 15);
      const float bv = (EPI == 3) ? 0.f : bias[col];
      #pragma unroll
      for (int q = 0; q < 4; ++q) {
        float v = acc[mi][ni][q] + bv;
        const size_t idx = (size_t)(row + q) * N + col;
        if (EPI == 0)      obf[idx] = f2bf(v);
        else if (EPI == 1) obf[idx] = f2bf(gelu_f(v));
        else if (EPI == 2) of32[idx] += v;
        else               of32[idx] = v;
      }
    }
  }
}

// ---------------- attention ----------------
template<int MASK>  // 0 = block_ntp, 1 = ar
__device__ __forceinline__ bool mask_ok(int r, int c) {
  if (r < 1024) return c <= r;
  if (MASK == 0) {
    const int ch = (r - 1024) >> 4;
    return (c < (ch << 4)) || (c >= 1024 + (ch << 4) && c < 1040 + (ch << 4));
  } else {
    return (c <= r - 1024) || (c == r);
  }
}

template<int MASK>
__global__ __launch_bounds__(256, 1)
void attn_kernel(const u16* __restrict__ qkv, u16* __restrict__ aout)
{
  __shared__ u16   Kt[128 * 72];    // [key][dh], padded 64->72 (2-way banks)
  __shared__ u16   Vt[64 * 136];    // [dh][key], padded 128->136
  __shared__ float Sf[128 * 128];   // scores f32
  __shared__ u16   Pt[128 * 136];   // probs bf16, padded
  __shared__ float rowr[128];
  __shared__ float rowl[128];

  const int tid = threadIdx.x;
  const int lane = tid & 63;
  const int w = tid >> 6;
  const int q0 = blockIdx.x << 7;
  const int h = blockIdx.y;
  const int b = blockIdx.z;
  const size_t base = (size_t)b * 2048 * 1536;

  // Q fragments in registers: wave w owns query rows q0+32w..+31
  bf16x8 qf[2][2];
  #pragma unroll
  for (int mi = 0; mi < 2; ++mi)
    #pragma unroll
    for (int kk = 0; kk < 2; ++kk)
      qf[mi][kk] = *(const bf16x8*)&qkv[base + (size_t)(q0 + w * 32 + mi * 16 + (lane & 15)) * 1536
                                        + h * 64 + kk * 32 + (lane >> 4) * 8];

  f32x4 of[2][4] = {};
  const int rr = tid >> 1, hf = tid & 1;   // softmax: 2 threads per row
  float m_r = -__builtin_inff(), l_r = 0.f;

  for (int kt = 0; kt < 16; ++kt) {
    const int kt0 = kt << 7;
    __syncthreads();
    // stage K (row-major padded) and V (transposed) via registers
    #pragma unroll
    for (int p = 0; p < 4; ++p) {
      const int key = p * 32 + (tid >> 3);
      const int dh0 = (tid & 7) << 3;
      const size_t rowb = base + (size_t)(kt0 + key) * 1536 + h * 64 + dh0;
      const bf16x8 kv = *(const bf16x8*)&qkv[rowb + 512];
      const bf16x8 vv = *(const bf16x8*)&qkv[rowb + 1024];
      *(bf16x8*)&Kt[key * 72 + dh0] = kv;
      #pragma unroll
      for (int j = 0; j < 8; ++j) Vt[(dh0 + j) * 136 + key] = (u16)vv[j];
    }
    __syncthreads();

    // S = (Q K^T) * 0.125, masked
    f32x4 sf[2][8] = {};
    #pragma unroll
    for (int kk = 0; kk < 2; ++kk) {
      bf16x8 kb[8];
      #pragma unroll
      for (int nj = 0; nj < 8; ++nj)
        kb[nj] = *(const bf16x8*)&Kt[(nj * 16 + (lane & 15)) * 72 + kk * 32 + (lane >> 4) * 8];
      #pragma unroll
      for (int mi = 0; mi < 2; ++mi)
        #pragma unroll
        for (int nj = 0; nj < 8; ++nj)
          sf[mi][nj] = __builtin_amdgcn_mfma_f32_16x16x32_bf16(qf[mi][kk], kb[nj], sf[mi][nj], 0, 0, 0);
    }
    #pragma unroll
    for (int mi = 0; mi < 2; ++mi)
      #pragma unroll
      for (int nj = 0; nj < 8; ++nj)
        #pragma unroll
        for (int q = 0; q < 4; ++q) {
          const int rl = w * 32 + mi * 16 + ((lane >> 4) << 2) + q;
          const int cl = nj * 16 + (lane & 15);
          float v = sf[mi][nj][q] * 0.125f;
          if (!mask_ok<MASK>(q0 + rl, kt0 + cl)) v = -1e9f;
          Sf[rl * 128 + cl] = v;
        }
    __syncthreads();

    // online softmax: 2 threads per row, rotated column order (bank spread)
    {
      const float* srow = &Sf[rr * 128];
      float tmax = -__builtin_inff();
      for (int j = 0; j < 64; ++j) {
        const int cc = (hf << 6) + ((j + rr) & 63);
        tmax = fmaxf(tmax, srow[cc]);
      }
      tmax = fmaxf(tmax, __shfl_xor(tmax, 1));
      const float mnew = fmaxf(m_r, tmax);
      const float corr = __expf(m_r - mnew);
      float ssum = 0.f;
      u16* prow = &Pt[rr * 136];
      for (int j = 0; j < 64; ++j) {
        const int cc = (hf << 6) + ((j + rr) & 63);
        const float p = __expf(srow[cc] - mnew);
        prow[cc] = f2bf(p);
        ssum += p;
      }
      ssum += __shfl_xor(ssum, 1);
      l_r = l_r * corr + ssum;
      m_r = mnew;
      if (!hf) rowr[rr] = corr;
    }
    __syncthreads();

    // rescale O, then O += P V
    #pragma unroll
    for (int mi = 0; mi < 2; ++mi)
      #pragma unroll
      for (int q = 0; q < 4; ++q) {
        const float c = rowr[w * 32 + mi * 16 + ((lane >> 4) << 2) + q];
        #pragma unroll
        for (int ni = 0; ni < 4; ++ni) of[mi][ni][q] *= c;
      }
    #pragma unroll
    for (int ks = 0; ks < 4; ++ks) {
      bf16x8 pa[2], vb[4];
      #pragma unroll
      for (int mi = 0; mi < 2; ++mi)
        pa[mi] = *(const bf16x8*)&Pt[(w * 32 + mi * 16 + (lane & 15)) * 136 + ks * 32 + (lane >> 4) * 8];
      #pragma unroll
      for (int ni = 0; ni < 4; ++ni)
        vb[ni] = *(const bf16x8*)&Vt[(ni * 16 + (lane & 15)) * 136 + ks * 32 + (lane >> 4) * 8];
      #pragma unroll
      for (int mi = 0; mi < 2; ++mi)
        #pragma unroll
        for (int ni = 0; ni < 4; ++ni)
          of[mi][ni] = __builtin_amdgcn_mfma_f32_16x16x32_bf16(pa[mi], vb[ni], of[mi][ni], 0, 0, 0);
    }
  }

  if (!hf) rowl[rr] = l_r;
  __syncthreads();
  #pragma unroll
  for (int mi = 0; mi < 2; ++mi)
    #pragma unroll
    for (int q = 0; q < 4; ++q) {
      const int rl = w * 32 + mi * 16 + ((lane >> 4) << 2) + q;
      const float inv = 1.0f / rowl[rl];
      #pragma unroll
      for (int ni = 0; ni < 4; ++ni)
        aout[(size_t)((b << 11) + q0 + rl) * 512 + h * 64 + ni * 16 + (lane & 15)]
            = f2bf(of[mi][ni][q] * inv);
    }
}

// ---------------- loss ----------------
__global__ __launch_bounds__(256)
void loss_row_kernel(const float* __restrict__ logits, const int* __restrict__ tok_ids,
                     float* __restrict__ nll)
{
  const int rb = blockIdx.x;           // 0..2045
  const int b = rb / 1023;
  const int i = rb - b * 1023;
  const float* row = logits + (size_t)((b << 11) + 1024 + i) * VOCAB;
  const int label = tok_ids[(b << 10) + i + 1];
  const int tid = threadIdx.x, lane = tid & 63, w = tid >> 6;
  __shared__ float red[4], red2[4];
  float mx = -__builtin_inff();
  for (int j = tid; j < VOCAB; j += 256) mx = fmaxf(mx, row[j]);
  #pragma unroll
  for (int o = 32; o; o >>= 1) mx = fmaxf(mx, __shfl_xor(mx, o));
  if (!lane) red[w] = mx;
  __syncthreads();
  mx = fmaxf(fmaxf(red[0], red[1]), fmaxf(red[2], red[3]));
  float s = 0.f;
  for (int j = tid; j < VOCAB; j += 256) s += __expf(row[j] - mx);
  #pragma unroll
  for (int o = 32; o; o >>= 1) s += __shfl_xor(s, o);
  if (!lane) red2[w] = s;
  __syncthreads();
  if (!tid) nll[rb] = logf(red2[0] + red2[1] + red2[2] + red2[3]) + mx - row[label];
}

__global__ __launch_bounds__(256)
void loss_reduce_kernel(const float* __restrict__ nll, float* __restrict__ out)
{
  const int tid = threadIdx.x, lane = tid & 63, w = tid >> 6;
  __shared__ float red[4];
  float s = 0.f;
  for (int j = tid; j < 2046; j += 256) s += nll[j];
  #pragma unroll
  for (int o = 32; o; o >>= 1) s += __shfl_xor(s, o);
  if (!lane) red[w] = s;
  __syncthreads();
  if (!tid) out[0] = (red[0] + red[1] + red[2] + red[3]) * (1.0f / 2046.0f);
}

// ---------------- host ----------------
extern "C" void kernel_launch(void* const* d_in, const int* in_sizes, int n_in,
                              void* d_out, int out_size, void* d_ws, size_t ws_size,
                              hipStream_t stream)
{
  (void)in_sizes; (void)n_in; (void)out_size; (void)ws_size;
  const int*   tok_ids  = (const int*)d_in[0];
  const float* tok_emb  = (const float*)d_in[1];
  const float* pos_emb  = (const float*)d_in[2];
  const float* mask_tok = (const float*)d_in[3];
  const float* ln_f_s   = (const float*)d_in[4];
  const float* ln_f_b   = (const float*)d_in[5];

  char* ws = (char*)d_ws;
  float* x    = (float*)(ws + 0);            // 4096*512 f32        (8388608 B)
  u16*   h    = (u16*)  (ws + 8388608);      // 4096*512 bf16       (4194304 B)
  u16*   qkvb = (u16*)  (ws + 12582912);     // 4096*1536 bf16      (12582912 B)
  u16*   att  = (u16*)  (ws + 25165824);     // 4096*512 bf16       (4194304 B)
  u16*   mid  = (u16*)  (ws + 29360128);     // 4096*2048 bf16      (16777216 B)
  u16*   wbf  = (u16*)  (ws + 46137344);     // 6 * 3145728 bf16    (37748736 B)
  u16*   tokb = (u16*)  (ws + 83886080);     // 32000*512 bf16      (32768000 B)
  float* nll  = (float*)(ws + 116654080);    // 2046 f32
  float* logits = (float*)d_out;             // 4096*32000 f32, then loss

  const dim3 tb(256);

  // ---- weight prep: f32 (K,N) -> bf16 (N,K); tok_emb is already (V,D)=(N,K)
  for (int l = 0; l < 6; ++l) {
    const int pi = (l < 4) ? 6 : 18;
    const int li = (l < 4) ? l : l - 4;
    u16* wl = wbf + (size_t)l * 3145728u;
    const float* Wqkv = (const float*)d_in[pi + 2]  + (size_t)li * 512 * 1536;
    const float* Wo   = (const float*)d_in[pi + 4]  + (size_t)li * 512 * 512;
    const float* W1   = (const float*)d_in[pi + 8]  + (size_t)li * 512 * 2048;
    const float* W2   = (const float*)d_in[pi + 10] + (size_t)li * 2048 * 512;
    transpose_cast_kernel<<<dim3(48, 16), dim3(32, 8), 0, stream>>>(Wqkv, wl,           512, 1536);
    transpose_cast_kernel<<<dim3(16, 16), dim3(32, 8), 0, stream>>>(Wo,   wl +  786432, 512,  512);
    transpose_cast_kernel<<<dim3(64, 16), dim3(32, 8), 0, stream>>>(W1,   wl + 1048576, 512, 2048);
    transpose_cast_kernel<<<dim3(16, 64), dim3(32, 8), 0, stream>>>(W2,   wl + 2097152, 2048, 512);
  }
  cast_bf16_kernel<<<16000, tb, 0, stream>>>(tok_emb, tokb, 16384000);

  embed_kernel<<<4096, tb, 0, stream>>>(tok_ids, tok_emb, pos_emb, mask_tok, x);

  for (int l = 0; l < 6; ++l) {
    const int pi = (l < 4) ? 6 : 18;
    const int li = (l < 4) ? l : l - 4;
    u16* wl = wbf + (size_t)l * 3145728u;
    const float* ln1s = (const float*)d_in[pi + 0]  + (size_t)li * 512;
    const float* ln1b = (const float*)d_in[pi + 1]  + (size_t)li * 512;
    const float* bqkv = (const float*)d_in[pi + 3]  + (size_t)li * 1536;
    const float* bo   = (const float*)d_in[pi + 5]  + (size_t)li * 512;
    const float* ln2s = (const float*)d_in[pi + 6]  + (size_t)li * 512;
    const float* ln2b = (const float*)d_in[pi + 7]  + (size_t)li * 512;
    const float* b1   = (const float*)d_in[pi + 9]  + (size_t)li * 2048;
    const float* b2   = (const float*)d_in[pi + 11] + (size_t)li * 512;

    ln_kernel<<<4096, tb, 0, stream>>>(x, ln1s, ln1b, h);
    gemm_kernel<0><<<dim3(12, 32), tb, 0, stream>>>(h, wl, bqkv, qkvb, nullptr, 4096, 1536, 512);
    if (l < 4) attn_kernel<0><<<dim3(16, 8, 2), tb, 0, stream>>>(qkvb, att);
    else       attn_kernel<1><<<dim3(16, 8, 2), tb, 0, stream>>>(qkvb, att);
    gemm_kernel<2><<<dim3(4, 32), tb, 0, stream>>>(att, wl + 786432, bo, nullptr, x, 4096, 512, 512);
    ln_kernel<<<4096, tb, 0, stream>>>(x, ln2s, ln2b, h);
    gemm_kernel<1><<<dim3(16, 32), tb, 0, stream>>>(h, wl + 1048576, b1, mid, nullptr, 4096, 2048, 512);
    gemm_kernel<2><<<dim3(4, 32), tb, 0, stream>>>(mid, wl + 2097152, b2, nullptr, x, 4096, 512, 2048);
  }

  ln_kernel<<<4096, tb, 0, stream>>>(x, ln_f_s, ln_f_b, h);
  gemm_kernel<3><<<dim3(250, 32), tb, 0, stream>>>(h, tokb, nullptr, nullptr, logits, 4096, 32000, 512);
  loss_row_kernel<<<2046, tb, 0, stream>>>(logits, tok_ids, nll);
  loss_reduce_kernel<<<1, tb, 0, stream>>>(nll, logits + (size_t)131072000);
}